// Round 6
// baseline (218.742 us; speedup 1.0000x reference)
//
#include <hip/hip_runtime.h>
#include <hip/hip_bf16.h>

#define BS   2
#define T    3
#define CCH  256
#define HH   48
#define WW   48
#define NH   8
#define NP   4
#define NL   3
#define DH   32
#define HWP  (HH*WW)     // 2304
#define LQ   (T*HWP)     // 6912
#define NIMG (BS*T)      // 6

typedef short v8s __attribute__((ext_vector_type(8)));
typedef float v4f __attribute__((ext_vector_type(4)));
typedef float v2f __attribute__((ext_vector_type(2)));
typedef unsigned int v2u __attribute__((ext_vector_type(2)));

__device__ __forceinline__ unsigned short f2b(float f) {
    unsigned u = __float_as_uint(f);
    return (unsigned short)((u + 0x7FFFu + ((u >> 16) & 1u)) >> 16);
}

#define GLOAD_LDS16(gp, lp) \
    __builtin_amdgcn_global_load_lds((const __attribute__((address_space(1))) unsigned int*)(const void*)(gp), \
                                     (__attribute__((address_space(3))) unsigned int*)(void*)(lp), 16, 0, 0)

// LDS layout (bytes): Abuf @0 (16K), slab @16384 (288*128=36864),
// zero-row @53248 (128). Total 53376 -> 3 blocks/CU (<= 163840/3).
#define LDS_SLAB  16384
#define LDS_ZROW  53248
#define LDS_TOTAL 53376

#define PBLK (NIMG*CCH*HWP)   // 3,538,944 floats per split-K partial

// ---------------------------------------------------------------------------
// Flow kernel: builds add[n][t][pix][l][2]  (fp32, tiny)
// ---------------------------------------------------------------------------
__global__ __launch_bounds__(256) void flow_kernel(
    const float* __restrict__ ff, const float* __restrict__ fb,
    float* __restrict__ addb)
{
    int idx = blockIdx.x * 256 + threadIdx.x;
    if (idx >= BS * HWP) return;
    int n = idx / HWP, pix = idx % HWP;
    int y = pix / WW, x = pix % WW;

    auto F = [&](const float* base, int i, int c, int p) {
        return base[n * (2*2*HWP) + i * (2*HWP) + c * HWP + p];
    };

    float f01x = F(ff,0,0,pix), f01y = F(ff,0,1,pix);
    float f12x = F(ff,1,0,pix), f12y = F(ff,1,1,pix);
    float b10x = F(fb,0,0,pix), b10y = F(fb,0,1,pix);
    float b21x = F(fb,1,0,pix), b21y = F(fb,1,1,pix);

    auto bil = [&](const float* base, int i, float fx, float fy, float* ox, float* oy) {
        float vx = (float)x + fx;
        float vy = (float)y + fy;
        float gx = 2.0f * vx / (float)(WW - 1) - 1.0f;
        float gy = 2.0f * vy / (float)(HH - 1) - 1.0f;
        float px = (gx + 1.0f) * 0.5f * (float)(WW - 1);
        float py = (gy + 1.0f) * 0.5f * (float)(HH - 1);
        px = fminf(fmaxf(px, 0.0f), (float)(WW - 1));
        py = fminf(fmaxf(py, 0.0f), (float)(HH - 1));
        float x0f = floorf(px), y0f = floorf(py);
        float wx1 = px - x0f, wx0 = 1.0f - wx1;
        float wy1 = py - y0f, wy0 = 1.0f - wy1;
        int xi0 = (int)x0f, yi0 = (int)y0f;
        int xc0 = min(max(xi0, 0), WW-1), xc1 = min(max(xi0+1, 0), WW-1);
        int yc0 = min(max(yi0, 0), HH-1), yc1 = min(max(yi0+1, 0), HH-1);
        float r[2];
        #pragma unroll
        for (int c = 0; c < 2; ++c) {
            float v00 = F(base, i, c, yc0*WW + xc0);
            float v10 = F(base, i, c, yc0*WW + xc1);
            float v01 = F(base, i, c, yc1*WW + xc0);
            float v11 = F(base, i, c, yc1*WW + xc1);
            r[c] = v00*(wx0*wy0) + v10*(wx1*wy0) + v01*(wx0*wy1) + v11*(wx1*wy1);
        }
        *ox = r[0]; *oy = r[1];
    };

    float wfx, wfy; bil(ff, 1, f01x, f01y, &wfx, &wfy);
    float f02x = f01x + wfx, f02y = f01y + wfy;
    float wbx, wby; bil(fb, 0, b21x, b21y, &wbx, &wby);
    float b20x = b21x + wbx, b20y = b21y + wby;

    float* A = addb + n * (3*HWP*6) + pix * 6;
    const int TS = HWP * 6;
    A[0] = 0.f;   A[1] = 0.f;   A[2] = f01x; A[3] = f01y; A[4] = f02x; A[5] = f02y;
    A[TS+0] = b10x; A[TS+1] = b10y; A[TS+2] = 0.f; A[TS+3] = 0.f; A[TS+4] = f12x; A[TS+5] = f12y;
    A[2*TS+0] = b20x; A[2*TS+1] = b20y; A[2*TS+2] = b21x; A[2*TS+3] = b21y; A[2*TS+4] = 0.f; A[2*TS+5] = 0.f;
}

// ---------------------------------------------------------------------------
// Weight transform: rows [0,M0) from s0, [M0,M1) from s1, [M1,Mpad) zero.
// dst[k][oc][ic] bf16.
// ---------------------------------------------------------------------------
__global__ __launch_bounds__(256) void wcvt2_kernel(
    const float* __restrict__ s0, const float* __restrict__ s1,
    unsigned short* __restrict__ dst, int M0, int M1, int Mpad)
{
    int idx = blockIdx.x * 256 + threadIdx.x;
    if (idx >= 9 * Mpad * 256) return;
    int k  = idx / (Mpad * 256);
    int oc = (idx / 256) % Mpad;
    int ic = idx % 256;
    float v = (oc < M0) ? s0[((size_t)oc * 256 + ic) * 9 + k]
            : (oc < M1) ? s1[((size_t)(oc - M0) * 256 + ic) * 9 + k] : 0.f;
    dst[idx] = f2b(v);
}

// ---------------------------------------------------------------------------
// Input transform: in[img][ic][px] fp32 -> out[img][px][ic] bf16
// ---------------------------------------------------------------------------
__global__ __launch_bounds__(256) void tcvt_kernel(
    const float* __restrict__ src, unsigned short* __restrict__ dst)
{
    __shared__ float lds[32][33];
    int px0 = blockIdx.x * 32, ic0 = blockIdx.y * 32, img = blockIdx.z;
    int t = threadIdx.x;
    #pragma unroll
    for (int s = 0; s < 4; ++s) {
        int icl = (t >> 5) + s * 8, pxl = t & 31;
        lds[icl][pxl] = src[((size_t)img * 256 + ic0 + icl) * HWP + px0 + pxl];
    }
    __syncthreads();
    #pragma unroll
    for (int s = 0; s < 4; ++s) {
        int pxl = (t >> 5) + s * 8, icl = t & 31;
        dst[((size_t)img * HWP + px0 + pxl) * 256 + ic0 + icl] = f2b(lds[icl][pxl]);
    }
}

// ---------------------------------------------------------------------------
// Slab implicit-GEMM conv: 128oc x 128px tile, 4 waves (64oc x 64px each).
// Single-buffer A (m97 2-barrier/full-drain tap loop) -> 53.4KB LDS,
// 3 blocks/CU. Per ic-chunk: slab staged once; 9 taps read shifted B-frags.
// phase 0: blocks [0,216) value conv (cls0), [216,540) off+attn (cls1).
// phase 1: split-K out conv (cls3): 432 blocks, s=b/216 does ic-chunks
//          [2s,2s+2), writes f32 partials (no bias) to outp.
// ---------------------------------------------------------------------------
__global__ __launch_bounds__(256) void convbig(
    int phase,
    const unsigned short* __restrict__ in_a,
    const unsigned short* __restrict__ in_b,
    const unsigned short* __restrict__ Wb_a,
    const unsigned short* __restrict__ Wb_b,
    const float* __restrict__ bias_a,
    const float* __restrict__ bias_off,
    const float* __restrict__ bias_attn,
    unsigned short* __restrict__ Vout,
    float* __restrict__ offb,
    float* __restrict__ attnb,
    float* __restrict__ outp,              // phase1: partial base
    const unsigned char* __restrict__ mask)
{
    __shared__ __align__(16) char lds[LDS_TOTAL];

    const int tid  = threadIdx.x;
    const int lane = tid & 63;
    const int wv   = tid >> 6;

    int b = blockIdx.x;
    int cls, mt, nt, img, Mpad, c_lo, c_hi, s;
    const unsigned short *inb, *Wb;
    if (phase == 0) {
        s = 0; c_lo = 0; c_hi = 4;
        if (b < 216) { cls = 0; mt = b % 2; int r = b / 2; nt = r % 18; img = r / 18;
                       inb = in_a; Wb = Wb_a; Mpad = 256; }
        else { b -= 216; cls = 1; mt = b % 3; int r = b / 3; nt = r % 18; img = r / 18;
               inb = in_b; Wb = Wb_b; Mpad = 384; }
    } else {
        cls = 3; s = b / 216; b = b % 216;
        c_lo = 2 * s; c_hi = c_lo + 2;
        mt = b % 2; int r = b / 2; nt = r % 18; img = r / 18;
        inb = in_a; Wb = Wb_a; Mpad = 256;
    }

    const int oc0 = mt * 128;
    const int pxb = nt * 128;
    const char* inIc = (const char*)(inb + (size_t)img * HWP * 256);
    const char* Wbc  = (const char*)Wb;

    // zero-row init (visible after first chunk barrier)
    if (tid < 8) {
        v8s z;
        #pragma unroll
        for (int j = 0; j < 8; ++j) z[j] = 0;
        *(v8s*)(lds + LDS_ZROW + tid * 16) = z;
    }

    // slab geometry
    const int r0   = pxb / 48;
    const int rlo  = (r0 > 0) ? (r0 - 1) : 0;
    const int pxlo = rlo * 48;

    const int lrow8 = lane >> 3;
    const int lcol  = lane & 7;

    // fragment geometry
    const int rowl = lane & 15;
    const int g    = lane >> 4;
    const int keyx = (rowl & 7) << 4;
    const int aoff0 = ((wv >> 1) * 64 + rowl) * 128;
    const int pxw   = pxb + (wv & 1) * 64;
    int ypx[4], xpx[4];
    #pragma unroll
    for (int p = 0; p < 4; ++p) {
        int px = pxw + p * 16 + rowl;
        ypx[p] = px / 48;
        xpx[p] = px % 48;
    }
    int ocr_[4];
    #pragma unroll
    for (int j = 0; j < 4; ++j) ocr_[j] = j * 32 + wv * 8 + lrow8;

    v4f acc[4][4];
    #pragma unroll
    for (int m = 0; m < 4; ++m)
        #pragma unroll
        for (int p = 0; p < 4; ++p)
            #pragma unroll
            for (int e = 0; e < 4; ++e) acc[m][p][e] = 0.f;

    for (int c = c_lo; c < c_hi; ++c) {
        const int ic0b = c * 128;

        __syncthreads();   // previous chunk's readers done (slab + A safe to overwrite)
        // ---- stage slab once per chunk ----
        #pragma unroll
        for (int rr = 0; rr < 9; ++rr) {
            int pe  = rr * 32 + wv * 8 + lrow8;
            int gpx = pxlo + pe;
            if (gpx > 2303) gpx = 2303;
            GLOAD_LDS16(inIc + (size_t)gpx * 512 + ic0b + ((lcol ^ (pe & 7)) << 4),
                        lds + LDS_SLAB + (rr * 32 + wv * 8) * 128);
        }

        for (int k = 0; k < 9; ++k) {
            if (k) __syncthreads();   // readers of A[k-1] done
            const char* wk = Wbc + (size_t)k * Mpad * 512;
            #pragma unroll
            for (int j = 0; j < 4; ++j) {
                GLOAD_LDS16(wk + (size_t)(oc0 + ocr_[j]) * 512 + ic0b + ((lcol ^ (ocr_[j] & 7)) << 4),
                            lds + (j * 32 + wv * 8) * 128);
            }
            __syncthreads();          // full drain (compiler waitcnt) + barrier

            const int dy = k / 3 - 1, dx = k % 3 - 1;
            int bbase[4], bkey[4];
            #pragma unroll
            for (int p = 0; p < 4; ++p) {
                int ys = ypx[p] + dy, xs = xpx[p] + dx;
                bool val = ((unsigned)ys < 48u) && ((unsigned)xs < 48u);
                int pe = ys * 48 + xs - pxlo;
                bbase[p] = val ? (LDS_SLAB + pe * 128) : LDS_ZROW;
                bkey[p]  = val ? ((pe & 7) << 4) : 0;
            }

            #pragma unroll
            for (int kk = 0; kk < 2; ++kk) {
                const int col = kk * 64 + g * 16;
                v8s a[4], bfr[4];
                #pragma unroll
                for (int m = 0; m < 4; ++m)
                    a[m] = *(const v8s*)(lds + aoff0 + m * 2048 + (col ^ keyx));
                #pragma unroll
                for (int p = 0; p < 4; ++p)
                    bfr[p] = *(const v8s*)(lds + bbase[p] + (col ^ bkey[p]));
                #pragma unroll
                for (int m = 0; m < 4; ++m)
                    #pragma unroll
                    for (int p = 0; p < 4; ++p)
                        acc[m][p] = __builtin_amdgcn_mfma_f32_16x16x32_bf16(a[m], bfr[p], acc[m][p], 0, 0, 0);
            }
        }
    }

    // ---- epilogue ----
    const int n = img / T, t = img % T;
    const int ocw = oc0 + (wv >> 1) * 64;

    #pragma unroll
    for (int p = 0; p < 4; ++p) {
        const int px_f = pxw + p * 16 + rowl;
        const int q = t * HWP + px_f;
        bool mk = (cls == 0) ? (mask[n * LQ + q] != 0) : false;
        #pragma unroll
        for (int m = 0; m < 4; ++m) {
            const int oc_f = ocw + m * 16 + g * 4;
            if (cls == 0) {
                unsigned short o[4];
                #pragma unroll
                for (int r = 0; r < 4; ++r) {
                    float v = acc[m][p][r] + bias_a[oc_f + r];
                    if (mk) v = 0.f;
                    o[r] = f2b(v);
                }
                int head = oc_f >> 5, d0 = oc_f & 31;
                v2u pk;
                pk[0] = (unsigned)o[0] | ((unsigned)o[1] << 16);
                pk[1] = (unsigned)o[2] | ((unsigned)o[3] << 16);
                *(v2u*)(Vout + (((size_t)(t * BS + n) * NH + head) * HWP + px_f) * 32 + d0) = pk;
            } else if (cls == 1) {
                if (oc_f < 192) {
                    v4f v;
                    #pragma unroll
                    for (int r = 0; r < 4; ++r) v[r] = acc[m][p][r] + bias_off[oc_f + r];
                    *(v4f*)(offb + ((size_t)n * LQ + q) * 192 + oc_f) = v;
                } else if (oc_f < 288) {
                    v4f v;
                    #pragma unroll
                    for (int r = 0; r < 4; ++r) v[r] = acc[m][p][r] + bias_attn[oc_f - 192 + r];
                    *(v4f*)(attnb + ((size_t)n * LQ + q) * 96 + (oc_f - 192)) = v;
                }
            } else {
                // split-K partial, no bias
                float* pb = outp + (size_t)s * PBLK;
                #pragma unroll
                for (int r = 0; r < 4; ++r)
                    pb[((size_t)img * CCH + oc_f + r) * HWP + px_f] = acc[m][p][r];
            }
        }
    }
}

// ---------------------------------------------------------------------------
// Split-K reduce: out = part0 + part1 + bias  (v4 vectorized)
// ---------------------------------------------------------------------------
__global__ __launch_bounds__(256) void reduce_kernel(
    const float* __restrict__ part, const float* __restrict__ bias,
    float* __restrict__ out)
{
    int i4 = blockIdx.x * 256 + threadIdx.x;
    size_t i = (size_t)i4 * 4;
    if (i >= (size_t)PBLK) return;
    int oc = (int)((i / HWP) % CCH);
    v4f a = *(const v4f*)(part + i);
    v4f b = *(const v4f*)(part + PBLK + i);
    float bv = bias[oc];
    v4f o;
    #pragma unroll
    for (int e = 0; e < 4; ++e) o[e] = a[e] + b[e] + bv;
    *(v4f*)(out + i) = o;
}

// ---------------------------------------------------------------------------
// Deformable sampling. 8-lane group per (n,q,head); lane owns 4 d-channels.
// ---------------------------------------------------------------------------
__global__ __launch_bounds__(256) void sample_kernel(
    const unsigned short* __restrict__ V,
    const float* __restrict__ offb,
    const float* __restrict__ attnb,
    const float* __restrict__ addb,
    const float* __restrict__ refp,
    unsigned short* __restrict__ midb)
{
    const int tid = threadIdx.x;
    const int gid = tid >> 3, li = tid & 7;
    const int pair = blockIdx.x * 32 + gid;
    const int head = pair & 7;
    const int nq = pair >> 3;
    const int n = nq / LQ, q = nq % LQ;
    const int t = q / HWP, pix = q % HWP;

    const float* al = attnb + ((size_t)n * LQ + q) * 96 + head * 12;
    float lg[12];
    {
        v4f t0 = *(const v4f*)al, t1 = *(const v4f*)(al + 4), t2 = *(const v4f*)(al + 8);
        #pragma unroll
        for (int j = 0; j < 4; ++j) { lg[j] = t0[j]; lg[4+j] = t1[j]; lg[8+j] = t2[j]; }
    }
    const float* ofp = offb + ((size_t)n * LQ + q) * 192 + head * 24;
    float of[24];
    #pragma unroll
    for (int j = 0; j < 6; ++j) {
        v4f v = *(const v4f*)(ofp + j * 4);
        #pragma unroll
        for (int e = 0; e < 4; ++e) of[j*4+e] = v[e];
    }
    const float* rpp = refp + ((size_t)n * LQ + q) * 6;
    const float* adp = addb + ((size_t)n * 3 * HWP + t * HWP + pix) * 6;
    float rp[6], ad[6];
    #pragma unroll
    for (int j = 0; j < 3; ++j) {
        v2f r = *(const v2f*)(rpp + j * 2);
        v2f a = *(const v2f*)(adp + j * 2);
        rp[j*2] = r[0]; rp[j*2+1] = r[1];
        ad[j*2] = a[0]; ad[j*2+1] = a[1];
    }

    float m = lg[0];
    #pragma unroll
    for (int j = 1; j < 12; ++j) m = fmaxf(m, lg[j]);
    float s = 0.f;
    #pragma unroll
    for (int j = 0; j < 12; ++j) { lg[j] = expf(lg[j] - m); s += lg[j]; }
    float inv = 1.0f / s;
    #pragma unroll
    for (int j = 0; j < 12; ++j) lg[j] *= inv;

    float acc0 = 0.f, acc1 = 0.f, acc2 = 0.f, acc3 = 0.f;

    #pragma unroll
    for (int l = 0; l < 3; ++l) {
        float refx = rp[l*2+0], refy = rp[l*2+1];
        float addx = ad[l*2+0], addy = ad[l*2+1];
        const unsigned short* Vi =
            V + (size_t)((l * BS + n) * NH + head) * HWP * DH + li * 4;
        #pragma unroll
        for (int p = 0; p < 4; ++p) {
            float ox = of[(l*4+p)*2+0] + addx;
            float oy = of[(l*4+p)*2+1] + addy;
            float locx = refx + ox * (1.0f/48.0f);
            float locy = refy + oy * (1.0f/48.0f);
            float gx = 2.0f*locx - 1.0f;
            float gy = 2.0f*locy - 1.0f;
            float pxf = ((gx + 1.0f) * 48.0f - 1.0f) * 0.5f;
            float pyf = ((gy + 1.0f) * 48.0f - 1.0f) * 0.5f;
            float x0f = floorf(pxf), y0f = floorf(pyf);
            float wx1 = pxf - x0f, wx0 = 1.0f - wx1;
            float wy1 = pyf - y0f, wy0 = 1.0f - wy1;
            int xi0 = (int)x0f, yi0 = (int)y0f;
            bool vx0 = (x0f >= 0.0f)     && (x0f <= 47.0f);
            bool vx1 = (x0f+1.f >= 0.0f) && (x0f+1.f <= 47.0f);
            bool vy0 = (y0f >= 0.0f)     && (y0f <= 47.0f);
            bool vy1 = (y0f+1.f >= 0.0f) && (y0f+1.f <= 47.0f);
            int xc0 = min(max(xi0, 0), 47),   xc1 = min(max(xi0+1, 0), 47);
            int yc0 = min(max(yi0, 0), 47),   yc1 = min(max(yi0+1, 0), 47);
            float aw = lg[l*4+p];
            float w00 = (vx0 && vy0) ? wx0*wy0*aw : 0.f;
            float w10 = (vx1 && vy0) ? wx1*wy0*aw : 0.f;
            float w01 = (vx0 && vy1) ? wx0*wy1*aw : 0.f;
            float w11 = (vx1 && vy1) ? wx1*wy1*aw : 0.f;
            v2u u00 = *(const v2u*)(Vi + (yc0*WW + xc0)*DH);
            v2u u10 = *(const v2u*)(Vi + (yc0*WW + xc1)*DH);
            v2u u01 = *(const v2u*)(Vi + (yc1*WW + xc0)*DH);
            v2u u11 = *(const v2u*)(Vi + (yc1*WW + xc1)*DH);
            #pragma unroll
            for (int c = 0; c < 4; ++c) {
                v2u u = (c == 0) ? u00 : (c == 1) ? u10 : (c == 2) ? u01 : u11;
                float w = (c == 0) ? w00 : (c == 1) ? w10 : (c == 2) ? w01 : w11;
                float f0 = __uint_as_float(u[0] << 16);
                float f1 = __uint_as_float(u[0] & 0xFFFF0000u);
                float f2 = __uint_as_float(u[1] << 16);
                float f3 = __uint_as_float(u[1] & 0xFFFF0000u);
                acc0 += w * f0; acc1 += w * f1; acc2 += w * f2; acc3 += w * f3;
            }
        }
    }

    unsigned short o0 = f2b(acc0), o1 = f2b(acc1), o2 = f2b(acc2), o3 = f2b(acc3);
    v2u pk;
    pk[0] = (unsigned)o0 | ((unsigned)o1 << 16);
    pk[1] = (unsigned)o2 | ((unsigned)o3 << 16);
    *(v2u*)(midb + ((size_t)(n * T + t) * HWP + pix) * 256 + head * 32 + li * 4) = pk;
}

// ---------------------------------------------------------------------------
extern "C" void kernel_launch(void* const* d_in, const int* in_sizes, int n_in,
                              void* d_out, int out_size, void* d_ws, size_t ws_size,
                              hipStream_t stream) {
    const float* query  = (const float*)d_in[0];
    const float* refp   = (const float*)d_in[1];
    const float* inputf = (const float*)d_in[2];
    const unsigned char* mask = (const unsigned char*)d_in[5];
    const float* ff     = (const float*)d_in[6];
    const float* fb     = (const float*)d_in[7];
    const float* w_off  = (const float*)d_in[8];
    const float* b_off  = (const float*)d_in[9];
    const float* w_attn = (const float*)d_in[10];
    const float* b_attn = (const float*)d_in[11];
    const float* w_val  = (const float*)d_in[12];
    const float* b_val  = (const float*)d_in[13];
    const float* w_out  = (const float*)d_in[14];
    const float* b_out  = (const float*)d_in[15];

    char* w = (char*)d_ws;
    float* offb  = (float*)w;           w += (size_t)BS*LQ*192*4;      // 10,616,832 B
    float* attnb = (float*)w;           w += (size_t)BS*LQ*96*4;       //  5,308,416
    float* addb  = (float*)w;           w += (size_t)BS*3*HWP*6*4;     //    331,776
    unsigned short* V      = (unsigned short*)w; w += (size_t)48*HWP*DH*2;   // 7,077,888
    unsigned short* inb_q  = (unsigned short*)w; w += (size_t)NIMG*HWP*256*2;// 7,077,888
    unsigned short* inb_v  = (unsigned short*)w; w += (size_t)NIMG*HWP*256*2;
    unsigned short* midb   = inb_v;  // alias: value conv done reading before sampler writes
    unsigned short* Wb_val = (unsigned short*)w; w += (size_t)9*256*256*2;
    unsigned short* Wb_oa  = (unsigned short*)w; w += (size_t)9*384*256*2;
    unsigned short* Wb_out = (unsigned short*)w; w += (size_t)9*256*256*2;
    // split-K partials alias offb..inb_q (all dead after sampler):
    // need 2*PBLK*4 = 28,311,552 B < 30,412,800 B available before inb_v.
    float* partial = (float*)d_ws;
    float* outp = (float*)d_out;

    flow_kernel<<<(BS*HWP + 255)/256, 256, 0, stream>>>(ff, fb, addb);
    wcvt2_kernel<<<9*256, 256, 0, stream>>>(w_val, w_val, Wb_val, 256, 256, 256);
    wcvt2_kernel<<<9*384, 256, 0, stream>>>(w_off, w_attn, Wb_oa, 192, 288, 384);
    wcvt2_kernel<<<9*256, 256, 0, stream>>>(w_out, w_out, Wb_out, 256, 256, 256);
    tcvt_kernel<<<dim3(HWP/32, 8, NIMG), 256, 0, stream>>>(inputf, inb_v);
    tcvt_kernel<<<dim3(HWP/32, 8, NIMG), 256, 0, stream>>>(query,  inb_q);

    convbig<<<540, 256, 0, stream>>>(0, inb_v, inb_q, Wb_val, Wb_oa,
                                     b_val, b_off, b_attn,
                                     V, offb, attnb, nullptr, mask);

    sample_kernel<<<(BS*LQ*NH)/32, 256, 0, stream>>>(V, offb, attnb, addb, refp, midb);

    convbig<<<432, 256, 0, stream>>>(1, midb, nullptr, Wb_out, nullptr,
                                     nullptr, nullptr, nullptr,
                                     nullptr, nullptr, nullptr, partial, nullptr);

    reduce_kernel<<<(PBLK/4 + 255)/256, 256, 0, stream>>>(partial, b_out, outp);
}

// Round 7
// 154.693 us; speedup vs baseline: 1.4140x; 1.4140x over previous
//
#include <hip/hip_runtime.h>
#include <hip/hip_bf16.h>

#define BS   2
#define T    3
#define CCH  256
#define HH   48
#define WW   48
#define NH   8
#define NP   4
#define NL   3
#define DH   32
#define HWP  (HH*WW)     // 2304
#define LQ   (T*HWP)     // 6912
#define NIMG (BS*T)      // 6

typedef short v8s __attribute__((ext_vector_type(8)));
typedef float v4f __attribute__((ext_vector_type(4)));
typedef float v2f __attribute__((ext_vector_type(2)));
typedef unsigned int v2u __attribute__((ext_vector_type(2)));

__device__ __forceinline__ unsigned short f2b(float f) {
    unsigned u = __float_as_uint(f);
    return (unsigned short)((u + 0x7FFFu + ((u >> 16) & 1u)) >> 16);
}

#define GLOAD_LDS16(gp, lp) \
    __builtin_amdgcn_global_load_lds((const __attribute__((address_space(1))) unsigned int*)(const void*)(gp), \
                                     (__attribute__((address_space(3))) unsigned int*)(void*)(lp), 16, 0, 0)

// LDS layout (bytes): Abuf0 @0 (16K), Abuf1 @16384, slab @32768 (288*128=36864),
// zero-row @69632 (128). Total 69760 -> 2 blocks/CU.
// NOTE r6 lesson: single-buffer A (3 blocks/CU) SERIALIZES the per-tap load
// latency and regressed 72->118us. Keep the dbuf + vmcnt(4) pipeline.
#define LDS_SLAB  32768
#define LDS_ZROW  69632
#define LDS_TOTAL 69760

#define PBLK (NIMG*CCH*HWP)   // 3,538,944 floats per split-K partial

// ---------------------------------------------------------------------------
// Flow kernel: builds add[n][t][pix][l][2]  (fp32, tiny)
// ---------------------------------------------------------------------------
__global__ __launch_bounds__(256) void flow_kernel(
    const float* __restrict__ ff, const float* __restrict__ fb,
    float* __restrict__ addb)
{
    int idx = blockIdx.x * 256 + threadIdx.x;
    if (idx >= BS * HWP) return;
    int n = idx / HWP, pix = idx % HWP;
    int y = pix / WW, x = pix % WW;

    auto F = [&](const float* base, int i, int c, int p) {
        return base[n * (2*2*HWP) + i * (2*HWP) + c * HWP + p];
    };

    float f01x = F(ff,0,0,pix), f01y = F(ff,0,1,pix);
    float f12x = F(ff,1,0,pix), f12y = F(ff,1,1,pix);
    float b10x = F(fb,0,0,pix), b10y = F(fb,0,1,pix);
    float b21x = F(fb,1,0,pix), b21y = F(fb,1,1,pix);

    auto bil = [&](const float* base, int i, float fx, float fy, float* ox, float* oy) {
        float vx = (float)x + fx;
        float vy = (float)y + fy;
        float gx = 2.0f * vx / (float)(WW - 1) - 1.0f;
        float gy = 2.0f * vy / (float)(HH - 1) - 1.0f;
        float px = (gx + 1.0f) * 0.5f * (float)(WW - 1);
        float py = (gy + 1.0f) * 0.5f * (float)(HH - 1);
        px = fminf(fmaxf(px, 0.0f), (float)(WW - 1));
        py = fminf(fmaxf(py, 0.0f), (float)(HH - 1));
        float x0f = floorf(px), y0f = floorf(py);
        float wx1 = px - x0f, wx0 = 1.0f - wx1;
        float wy1 = py - y0f, wy0 = 1.0f - wy1;
        int xi0 = (int)x0f, yi0 = (int)y0f;
        int xc0 = min(max(xi0, 0), WW-1), xc1 = min(max(xi0+1, 0), WW-1);
        int yc0 = min(max(yi0, 0), HH-1), yc1 = min(max(yi0+1, 0), HH-1);
        float r[2];
        #pragma unroll
        for (int c = 0; c < 2; ++c) {
            float v00 = F(base, i, c, yc0*WW + xc0);
            float v10 = F(base, i, c, yc0*WW + xc1);
            float v01 = F(base, i, c, yc1*WW + xc0);
            float v11 = F(base, i, c, yc1*WW + xc1);
            r[c] = v00*(wx0*wy0) + v10*(wx1*wy0) + v01*(wx0*wy1) + v11*(wx1*wy1);
        }
        *ox = r[0]; *oy = r[1];
    };

    float wfx, wfy; bil(ff, 1, f01x, f01y, &wfx, &wfy);
    float f02x = f01x + wfx, f02y = f01y + wfy;
    float wbx, wby; bil(fb, 0, b21x, b21y, &wbx, &wby);
    float b20x = b21x + wbx, b20y = b21y + wby;

    float* A = addb + n * (3*HWP*6) + pix * 6;
    const int TS = HWP * 6;
    A[0] = 0.f;   A[1] = 0.f;   A[2] = f01x; A[3] = f01y; A[4] = f02x; A[5] = f02y;
    A[TS+0] = b10x; A[TS+1] = b10y; A[TS+2] = 0.f; A[TS+3] = 0.f; A[TS+4] = f12x; A[TS+5] = f12y;
    A[2*TS+0] = b20x; A[2*TS+1] = b20y; A[2*TS+2] = b21x; A[2*TS+3] = b21y; A[2*TS+4] = 0.f; A[2*TS+5] = 0.f;
}

// ---------------------------------------------------------------------------
// Weight transform: rows [0,M0) from s0, [M0,M1) from s1, [M1,Mpad) zero.
// dst[k][oc][ic] bf16.
// ---------------------------------------------------------------------------
__global__ __launch_bounds__(256) void wcvt2_kernel(
    const float* __restrict__ s0, const float* __restrict__ s1,
    unsigned short* __restrict__ dst, int M0, int M1, int Mpad)
{
    int idx = blockIdx.x * 256 + threadIdx.x;
    if (idx >= 9 * Mpad * 256) return;
    int k  = idx / (Mpad * 256);
    int oc = (idx / 256) % Mpad;
    int ic = idx % 256;
    float v = (oc < M0) ? s0[((size_t)oc * 256 + ic) * 9 + k]
            : (oc < M1) ? s1[((size_t)(oc - M0) * 256 + ic) * 9 + k] : 0.f;
    dst[idx] = f2b(v);
}

// ---------------------------------------------------------------------------
// Input transform: in[img][ic][px] fp32 -> out[img][px][ic] bf16
// ---------------------------------------------------------------------------
__global__ __launch_bounds__(256) void tcvt_kernel(
    const float* __restrict__ src, unsigned short* __restrict__ dst)
{
    __shared__ float lds[32][33];
    int px0 = blockIdx.x * 32, ic0 = blockIdx.y * 32, img = blockIdx.z;
    int t = threadIdx.x;
    #pragma unroll
    for (int s = 0; s < 4; ++s) {
        int icl = (t >> 5) + s * 8, pxl = t & 31;
        lds[icl][pxl] = src[((size_t)img * 256 + ic0 + icl) * HWP + px0 + pxl];
    }
    __syncthreads();
    #pragma unroll
    for (int s = 0; s < 4; ++s) {
        int pxl = (t >> 5) + s * 8, icl = t & 31;
        dst[((size_t)img * HWP + px0 + pxl) * 256 + ic0 + icl] = f2b(lds[icl][pxl]);
    }
}

// ---------------------------------------------------------------------------
// Slab implicit-GEMM conv (r5 structure): 128oc x 128px tile, 4 waves.
// Per ic-chunk (64 ch): stage input slab ONCE (288 px incl. halo), then loop
// 9 taps with DOUBLE-BUFFERED weight staging + counted vmcnt(4) (A[k+1] in
// flight across barriers). B-fragments read shifted from slab; OOB -> zero-row.
// phase 0: blocks [0,216) value conv (cls0), [216,540) off+attn (cls1).
// phase 1: split-K out conv (cls3): 432 blocks, s=b/216 does ic-chunks
//          [2s,2s+2), writes f32 partials (no bias).
// ---------------------------------------------------------------------------
__global__ __launch_bounds__(256) void convbig(
    int phase,
    const unsigned short* __restrict__ in_a,
    const unsigned short* __restrict__ in_b,
    const unsigned short* __restrict__ Wb_a,
    const unsigned short* __restrict__ Wb_b,
    const float* __restrict__ bias_a,
    const float* __restrict__ bias_off,
    const float* __restrict__ bias_attn,
    unsigned short* __restrict__ Vout,
    float* __restrict__ offb,
    float* __restrict__ attnb,
    float* __restrict__ outp,              // phase1: partial base
    const unsigned char* __restrict__ mask)
{
    __shared__ __align__(16) char lds[LDS_TOTAL];

    const int tid  = threadIdx.x;
    const int lane = tid & 63;
    const int wv   = tid >> 6;

    int b = blockIdx.x;
    int cls, mt, nt, img, Mpad, c_lo, c_hi, s;
    const unsigned short *inb, *Wb;
    if (phase == 0) {
        s = 0; c_lo = 0; c_hi = 4;
        if (b < 216) { cls = 0; mt = b % 2; int r = b / 2; nt = r % 18; img = r / 18;
                       inb = in_a; Wb = Wb_a; Mpad = 256; }
        else { b -= 216; cls = 1; mt = b % 3; int r = b / 3; nt = r % 18; img = r / 18;
               inb = in_b; Wb = Wb_b; Mpad = 384; }
    } else {
        cls = 3; s = b / 216; b = b % 216;
        c_lo = 2 * s; c_hi = c_lo + 2;
        mt = b % 2; int r = b / 2; nt = r % 18; img = r / 18;
        inb = in_a; Wb = Wb_a; Mpad = 256;
    }

    const int oc0 = mt * 128;
    const int pxb = nt * 128;
    const char* inIc = (const char*)(inb + (size_t)img * HWP * 256);
    const char* Wbc  = (const char*)Wb;

    // zero-row init (visible after first chunk's full drain + barrier)
    if (tid < 8) {
        v8s z;
        #pragma unroll
        for (int j = 0; j < 8; ++j) z[j] = 0;
        *(v8s*)(lds + LDS_ZROW + tid * 16) = z;
    }

    // slab geometry
    const int r0   = pxb / 48;
    const int rlo  = (r0 > 0) ? (r0 - 1) : 0;
    const int pxlo = rlo * 48;

    const int lrow8 = lane >> 3;
    const int lcol  = lane & 7;

    // fragment geometry
    const int rowl = lane & 15;
    const int g    = lane >> 4;
    const int keyx = (rowl & 7) << 4;
    const int aoff0 = ((wv >> 1) * 64 + rowl) * 128;
    const int pxw   = pxb + (wv & 1) * 64;
    int ypx[4], xpx[4];
    #pragma unroll
    for (int p = 0; p < 4; ++p) {
        int px = pxw + p * 16 + rowl;
        ypx[p] = px / 48;
        xpx[p] = px % 48;
    }
    int ocr_[4];
    #pragma unroll
    for (int j = 0; j < 4; ++j) ocr_[j] = j * 32 + wv * 8 + lrow8;

    v4f acc[4][4];
    #pragma unroll
    for (int m = 0; m < 4; ++m)
        #pragma unroll
        for (int p = 0; p < 4; ++p)
            #pragma unroll
            for (int e = 0; e < 4; ++e) acc[m][p][e] = 0.f;

    for (int c = c_lo; c < c_hi; ++c) {
        const int ic0b = c * 128;   // byte offset of ic-chunk within 512B px row

        // ---- stage slab (288 px-entries x 128 B), linear dest, pre-swizzled src ----
        #pragma unroll
        for (int rr = 0; rr < 9; ++rr) {
            int pe  = rr * 32 + wv * 8 + lrow8;
            int gpx = pxlo + pe;
            if (gpx > 2303) gpx = 2303;
            GLOAD_LDS16(inIc + (size_t)gpx * 512 + ic0b + ((lcol ^ (pe & 7)) << 4),
                        lds + LDS_SLAB + (rr * 32 + wv * 8) * 128);
        }
        // ---- stage A tap0 -> buf0 ----
        #pragma unroll
        for (int j = 0; j < 4; ++j) {
            GLOAD_LDS16(Wbc + (size_t)(oc0 + ocr_[j]) * 512 + ic0b + ((lcol ^ (ocr_[j] & 7)) << 4),
                        lds + (j * 32 + wv * 8) * 128);
        }
        asm volatile("s_waitcnt vmcnt(0) lgkmcnt(0)" ::: "memory");
        __builtin_amdgcn_s_barrier();

        for (int k = 0; k < 9; ++k) {
            const int dy = k / 3 - 1, dx = k % 3 - 1;
            const int cur = k & 1;
            if (k < 8) {
                const char* wk1 = Wbc + (size_t)(k + 1) * Mpad * 512;
                #pragma unroll
                for (int j = 0; j < 4; ++j) {
                    GLOAD_LDS16(wk1 + (size_t)(oc0 + ocr_[j]) * 512 + ic0b + ((lcol ^ (ocr_[j] & 7)) << 4),
                                lds + (cur ^ 1) * 16384 + (j * 32 + wv * 8) * 128);
                }
                asm volatile("s_waitcnt vmcnt(4)" ::: "memory");
            } else {
                asm volatile("s_waitcnt vmcnt(0)" ::: "memory");
            }
            __builtin_amdgcn_s_barrier();

            // B addresses for this tap
            int bbase[4], bkey[4];
            #pragma unroll
            for (int p = 0; p < 4; ++p) {
                int ys = ypx[p] + dy, xs = xpx[p] + dx;
                bool val = ((unsigned)ys < 48u) && ((unsigned)xs < 48u);
                int pe = ys * 48 + xs - pxlo;
                bbase[p] = val ? (LDS_SLAB + pe * 128) : LDS_ZROW;
                bkey[p]  = val ? ((pe & 7) << 4) : 0;
            }

            #pragma unroll
            for (int kk = 0; kk < 2; ++kk) {
                const int col = kk * 64 + g * 16;
                v8s a[4], bfr[4];
                #pragma unroll
                for (int m = 0; m < 4; ++m)
                    a[m] = *(const v8s*)(lds + cur * 16384 + aoff0 + m * 2048 + (col ^ keyx));
                #pragma unroll
                for (int p = 0; p < 4; ++p)
                    bfr[p] = *(const v8s*)(lds + bbase[p] + (col ^ bkey[p]));
                #pragma unroll
                for (int m = 0; m < 4; ++m)
                    #pragma unroll
                    for (int p = 0; p < 4; ++p)
                        acc[m][p] = __builtin_amdgcn_mfma_f32_16x16x32_bf16(a[m], bfr[p], acc[m][p], 0, 0, 0);
            }
            __builtin_amdgcn_s_barrier();
        }
    }

    // ---- epilogue ----
    const int n = img / T, t = img % T;
    const int ocw = oc0 + (wv >> 1) * 64;

    #pragma unroll
    for (int p = 0; p < 4; ++p) {
        const int px_f = pxw + p * 16 + rowl;
        const int q = t * HWP + px_f;
        bool mk = (cls == 0) ? (mask[n * LQ + q] != 0) : false;
        #pragma unroll
        for (int m = 0; m < 4; ++m) {
            const int oc_f = ocw + m * 16 + g * 4;
            if (cls == 0) {
                unsigned short o[4];
                #pragma unroll
                for (int r = 0; r < 4; ++r) {
                    float v = acc[m][p][r] + bias_a[oc_f + r];
                    if (mk) v = 0.f;
                    o[r] = f2b(v);
                }
                int head = oc_f >> 5, d0 = oc_f & 31;
                v2u pk;
                pk[0] = (unsigned)o[0] | ((unsigned)o[1] << 16);
                pk[1] = (unsigned)o[2] | ((unsigned)o[3] << 16);
                *(v2u*)(Vout + (((size_t)(t * BS + n) * NH + head) * HWP + px_f) * 32 + d0) = pk;
            } else if (cls == 1) {
                if (oc_f < 192) {
                    v4f v;
                    #pragma unroll
                    for (int r = 0; r < 4; ++r) v[r] = acc[m][p][r] + bias_off[oc_f + r];
                    *(v4f*)(offb + ((size_t)n * LQ + q) * 192 + oc_f) = v;
                } else if (oc_f < 288) {
                    v4f v;
                    #pragma unroll
                    for (int r = 0; r < 4; ++r) v[r] = acc[m][p][r] + bias_attn[oc_f - 192 + r];
                    *(v4f*)(attnb + ((size_t)n * LQ + q) * 96 + (oc_f - 192)) = v;
                }
            } else {
                // split-K partial, no bias
                float* pb = outp + (size_t)s * PBLK;
                #pragma unroll
                for (int r = 0; r < 4; ++r)
                    pb[((size_t)img * CCH + oc_f + r) * HWP + px_f] = acc[m][p][r];
            }
        }
    }
}

// ---------------------------------------------------------------------------
// Split-K reduce: out = part0 + part1 + bias  (v4 vectorized)
// ---------------------------------------------------------------------------
__global__ __launch_bounds__(256) void reduce_kernel(
    const float* __restrict__ part, const float* __restrict__ bias,
    float* __restrict__ out)
{
    int i4 = blockIdx.x * 256 + threadIdx.x;
    size_t i = (size_t)i4 * 4;
    if (i >= (size_t)PBLK) return;
    int oc = (int)((i / HWP) % CCH);
    v4f a = *(const v4f*)(part + i);
    v4f b = *(const v4f*)(part + PBLK + i);
    float bv = bias[oc];
    v4f o;
    #pragma unroll
    for (int e = 0; e < 4; ++e) o[e] = a[e] + b[e] + bv;
    *(v4f*)(out + i) = o;
}

// ---------------------------------------------------------------------------
// Deformable sampling. 8-lane group per (n,q,head); lane owns 4 d-channels.
// ---------------------------------------------------------------------------
__global__ __launch_bounds__(256) void sample_kernel(
    const unsigned short* __restrict__ V,
    const float* __restrict__ offb,
    const float* __restrict__ attnb,
    const float* __restrict__ addb,
    const float* __restrict__ refp,
    unsigned short* __restrict__ midb)
{
    const int tid = threadIdx.x;
    const int gid = tid >> 3, li = tid & 7;
    const int pair = blockIdx.x * 32 + gid;
    const int head = pair & 7;
    const int nq = pair >> 3;
    const int n = nq / LQ, q = nq % LQ;
    const int t = q / HWP, pix = q % HWP;

    const float* al = attnb + ((size_t)n * LQ + q) * 96 + head * 12;
    float lg[12];
    {
        v4f t0 = *(const v4f*)al, t1 = *(const v4f*)(al + 4), t2 = *(const v4f*)(al + 8);
        #pragma unroll
        for (int j = 0; j < 4; ++j) { lg[j] = t0[j]; lg[4+j] = t1[j]; lg[8+j] = t2[j]; }
    }
    const float* ofp = offb + ((size_t)n * LQ + q) * 192 + head * 24;
    float of[24];
    #pragma unroll
    for (int j = 0; j < 6; ++j) {
        v4f v = *(const v4f*)(ofp + j * 4);
        #pragma unroll
        for (int e = 0; e < 4; ++e) of[j*4+e] = v[e];
    }
    const float* rpp = refp + ((size_t)n * LQ + q) * 6;
    const float* adp = addb + ((size_t)n * 3 * HWP + t * HWP + pix) * 6;
    float rp[6], ad[6];
    #pragma unroll
    for (int j = 0; j < 3; ++j) {
        v2f r = *(const v2f*)(rpp + j * 2);
        v2f a = *(const v2f*)(adp + j * 2);
        rp[j*2] = r[0]; rp[j*2+1] = r[1];
        ad[j*2] = a[0]; ad[j*2+1] = a[1];
    }

    float m = lg[0];
    #pragma unroll
    for (int j = 1; j < 12; ++j) m = fmaxf(m, lg[j]);
    float s = 0.f;
    #pragma unroll
    for (int j = 0; j < 12; ++j) { lg[j] = expf(lg[j] - m); s += lg[j]; }
    float inv = 1.0f / s;
    #pragma unroll
    for (int j = 0; j < 12; ++j) lg[j] *= inv;

    float acc0 = 0.f, acc1 = 0.f, acc2 = 0.f, acc3 = 0.f;

    #pragma unroll
    for (int l = 0; l < 3; ++l) {
        float refx = rp[l*2+0], refy = rp[l*2+1];
        float addx = ad[l*2+0], addy = ad[l*2+1];
        const unsigned short* Vi =
            V + (size_t)((l * BS + n) * NH + head) * HWP * DH + li * 4;
        #pragma unroll
        for (int p = 0; p < 4; ++p) {
            float ox = of[(l*4+p)*2+0] + addx;
            float oy = of[(l*4+p)*2+1] + addy;
            float locx = refx + ox * (1.0f/48.0f);
            float locy = refy + oy * (1.0f/48.0f);
            float gx = 2.0f*locx - 1.0f;
            float gy = 2.0f*locy - 1.0f;
            float pxf = ((gx + 1.0f) * 48.0f - 1.0f) * 0.5f;
            float pyf = ((gy + 1.0f) * 48.0f - 1.0f) * 0.5f;
            float x0f = floorf(pxf), y0f = floorf(pyf);
            float wx1 = pxf - x0f, wx0 = 1.0f - wx1;
            float wy1 = pyf - y0f, wy0 = 1.0f - wy1;
            int xi0 = (int)x0f, yi0 = (int)y0f;
            bool vx0 = (x0f >= 0.0f)     && (x0f <= 47.0f);
            bool vx1 = (x0f+1.f >= 0.0f) && (x0f+1.f <= 47.0f);
            bool vy0 = (y0f >= 0.0f)     && (y0f <= 47.0f);
            bool vy1 = (y0f+1.f >= 0.0f) && (y0f+1.f <= 47.0f);
            int xc0 = min(max(xi0, 0), 47),   xc1 = min(max(xi0+1, 0), 47);
            int yc0 = min(max(yi0, 0), 47),   yc1 = min(max(yi0+1, 0), 47);
            float aw = lg[l*4+p];
            float w00 = (vx0 && vy0) ? wx0*wy0*aw : 0.f;
            float w10 = (vx1 && vy0) ? wx1*wy0*aw : 0.f;
            float w01 = (vx0 && vy1) ? wx0*wy1*aw : 0.f;
            float w11 = (vx1 && vy1) ? wx1*wy1*aw : 0.f;
            v2u u00 = *(const v2u*)(Vi + (yc0*WW + xc0)*DH);
            v2u u10 = *(const v2u*)(Vi + (yc0*WW + xc1)*DH);
            v2u u01 = *(const v2u*)(Vi + (yc1*WW + xc0)*DH);
            v2u u11 = *(const v2u*)(Vi + (yc1*WW + xc1)*DH);
            #pragma unroll
            for (int c = 0; c < 4; ++c) {
                v2u u = (c == 0) ? u00 : (c == 1) ? u10 : (c == 2) ? u01 : u11;
                float w = (c == 0) ? w00 : (c == 1) ? w10 : (c == 2) ? w01 : w11;
                float f0 = __uint_as_float(u[0] << 16);
                float f1 = __uint_as_float(u[0] & 0xFFFF0000u);
                float f2 = __uint_as_float(u[1] << 16);
                float f3 = __uint_as_float(u[1] & 0xFFFF0000u);
                acc0 += w * f0; acc1 += w * f1; acc2 += w * f2; acc3 += w * f3;
            }
        }
    }

    unsigned short o0 = f2b(acc0), o1 = f2b(acc1), o2 = f2b(acc2), o3 = f2b(acc3);
    v2u pk;
    pk[0] = (unsigned)o0 | ((unsigned)o1 << 16);
    pk[1] = (unsigned)o2 | ((unsigned)o3 << 16);
    *(v2u*)(midb + ((size_t)(n * T + t) * HWP + pix) * 256 + head * 32 + li * 4) = pk;
}

// ---------------------------------------------------------------------------
extern "C" void kernel_launch(void* const* d_in, const int* in_sizes, int n_in,
                              void* d_out, int out_size, void* d_ws, size_t ws_size,
                              hipStream_t stream) {
    const float* query  = (const float*)d_in[0];
    const float* refp   = (const float*)d_in[1];
    const float* inputf = (const float*)d_in[2];
    const unsigned char* mask = (const unsigned char*)d_in[5];
    const float* ff     = (const float*)d_in[6];
    const float* fb     = (const float*)d_in[7];
    const float* w_off  = (const float*)d_in[8];
    const float* b_off  = (const float*)d_in[9];
    const float* w_attn = (const float*)d_in[10];
    const float* b_attn = (const float*)d_in[11];
    const float* w_val  = (const float*)d_in[12];
    const float* b_val  = (const float*)d_in[13];
    const float* w_out  = (const float*)d_in[14];
    const float* b_out  = (const float*)d_in[15];

    char* w = (char*)d_ws;
    float* offb  = (float*)w;           w += (size_t)BS*LQ*192*4;      // 10,616,832 B
    float* attnb = (float*)w;           w += (size_t)BS*LQ*96*4;       //  5,308,416
    float* addb  = (float*)w;           w += (size_t)BS*3*HWP*6*4;     //    331,776
    unsigned short* V      = (unsigned short*)w; w += (size_t)48*HWP*DH*2;   // 7,077,888
    unsigned short* inb_q  = (unsigned short*)w; w += (size_t)NIMG*HWP*256*2;// 7,077,888
    unsigned short* inb_v  = (unsigned short*)w; w += (size_t)NIMG*HWP*256*2;
    unsigned short* midb   = inb_v;  // alias: value conv done reading before sampler writes
    unsigned short* Wb_val = (unsigned short*)w; w += (size_t)9*256*256*2;
    unsigned short* Wb_oa  = (unsigned short*)w; w += (size_t)9*384*256*2;
    unsigned short* Wb_out = (unsigned short*)w; w += (size_t)9*256*256*2;
    // split-K partials alias offb..inb_q (dead after sampler):
    // 2*PBLK*4 = 28,311,552 B < 30,412,800 B (offset of inb_v). midb/Wb safe.
    float* partial = (float*)d_ws;
    float* outp = (float*)d_out;

    flow_kernel<<<(BS*HWP + 255)/256, 256, 0, stream>>>(ff, fb, addb);
    wcvt2_kernel<<<9*256, 256, 0, stream>>>(w_val, w_val, Wb_val, 256, 256, 256);
    wcvt2_kernel<<<9*384, 256, 0, stream>>>(w_off, w_attn, Wb_oa, 192, 288, 384);
    wcvt2_kernel<<<9*256, 256, 0, stream>>>(w_out, w_out, Wb_out, 256, 256, 256);
    tcvt_kernel<<<dim3(HWP/32, 8, NIMG), 256, 0, stream>>>(inputf, inb_v);
    tcvt_kernel<<<dim3(HWP/32, 8, NIMG), 256, 0, stream>>>(query,  inb_q);

    convbig<<<540, 256, 0, stream>>>(0, inb_v, inb_q, Wb_val, Wb_oa,
                                     b_val, b_off, b_attn,
                                     V, offb, attnb, nullptr, mask);

    sample_kernel<<<(BS*LQ*NH)/32, 256, 0, stream>>>(V, offb, attnb, addb, refp, midb);

    convbig<<<432, 256, 0, stream>>>(1, midb, nullptr, Wb_out, nullptr,
                                     nullptr, nullptr, nullptr,
                                     nullptr, nullptr, nullptr, partial, nullptr);

    reduce_kernel<<<(PBLK/4 + 255)/256, 256, 0, stream>>>(partial, b_out, outp);
}